// Round 9
// baseline (131.841 us; speedup 1.0000x reference)
//
#include <hip/hip_runtime.h>
#include <cstdint>

#define BB 2
#define NN 4096
#define MM 4096
#define KK 32
#define CC 64
#define R2C 0.0064f   // RADIUS^2

typedef _Float16 v8h __attribute__((ext_vector_type(8)));
typedef _Float16 v4h __attribute__((ext_vector_type(4)));
typedef float    v4f __attribute__((ext_vector_type(4)));

#define TC  64     // MLP columns per pass
#define XS  104    // X  stride (f16): 96 + 8 pad
#define H1S 136    // H1 stride: 128 + 8
#define H2S 72     // H2 stride: 64 + 8

// ---------------------------------------------------------------------------
// Dispatch 1: scan + setup (no inter-block dependencies).
//   blocks [  0, 256): SELECT 32 points/block (8/wave). knn chunks staged to
//                      LDS from the RAW (B,3,M) layout with |k|^2 computed in
//                      the staging pass (identical fp32 op order -> identical
//                      d2 bits -> identical selection). Ballot-compaction of
//                      first-KK ascending in-radius m == reference
//                      top_k-of-masked-index. Row-min -> unique loss slot.
//   blocks [256, 512): COLMIN 32 m/block (8/wave), points staged likewise.
//   blocks [512, 640): transpose feat (B,C,M) -> featH (B,M,C) f16.
//   blocks [640, 688): pack weights to f16 A-operand layouts.
// Loss: per-wave plain store to a unique slot (no atomics, no zeroing).
// 32 pts/block halves staged-tile L2 traffic vs R8 (16/block).
// ---------------------------------------------------------------------------
__launch_bounds__(256)
__global__ void scan_setup_kernel(const float* __restrict__ points,
                                  const float* __restrict__ knn,
                                  const float* __restrict__ feat,
                                  const float* __restrict__ w1,
                                  const float* __restrict__ w2,
                                  const float* __restrict__ w3,
                                  _Float16* __restrict__ featH,
                                  _Float16* __restrict__ w1h,
                                  _Float16* __restrict__ w2h,
                                  _Float16* __restrict__ w3h,
                                  int* __restrict__ idx_ws,
                                  float* __restrict__ lossbuf) {
    __shared__ __align__(16) char SM[16640];   // union: float4[1024] | float[64][65]
    __shared__ int sidx[32][KK];
    float4* tile = (float4*)SM;
    int t = threadIdx.x;
    int w = t >> 6, lane = t & 63;
    int blk = blockIdx.x;

    if (blk < 256) {
        // ---------------- select: 32 points, 8 per wave ----------------
        int pt0 = blk * 32;                  // global point id (b*NN+n)
        int b = blk >> 7;
        const float* pp = points + (size_t)b * 3 * NN;
        const float* kp = knn + (size_t)b * 3 * MM;
        float4 P[8];
#pragma unroll
        for (int p = 0; p < 8; ++p) {
            int nl = (pt0 & (NN - 1)) + 8 * w + p;
            float x = pp[nl], y = pp[NN + nl], z = pp[2 * NN + nl];
            float e = __fadd_rn(__fadd_rn(__fmul_rn(x, x), __fmul_rn(y, y)),
                                __fmul_rn(z, z));
            P[p] = make_float4(x, y, z, e);
        }
        int cnt[8] = {0, 0, 0, 0, 0, 0, 0, 0};
        float mn[8];
#pragma unroll
        for (int p = 0; p < 8; ++p) mn[p] = 1e30f;

        for (int ch = 0; ch < 4; ++ch) {
            const float* kx = kp + ch * 1024;
#pragma unroll
            for (int j = 0; j < 4; ++j) {
                int i = t + 256 * j;
                float x = kx[i], y = kx[MM + i], z = kx[2 * MM + i];
                float e = __fadd_rn(__fadd_rn(__fmul_rn(x, x), __fmul_rn(y, y)),
                                    __fmul_rn(z, z));
                tile[i] = make_float4(x, y, z, e);
            }
            __syncthreads();
#pragma unroll 1
            for (int i = 0; i < 16; ++i) {
                float4 k4 = tile[i * 64 + lane];
                int m = ch * 1024 + i * 64 + lane;
#pragma unroll
                for (int p = 0; p < 8; ++p) {
                    float cross = __builtin_fmaf(P[p].z, k4.z,
                                  __builtin_fmaf(P[p].y, k4.y,
                                                 __fmul_rn(P[p].x, k4.x)));
                    float d2 = __fsub_rn(__fadd_rn(P[p].w, k4.w),
                                         __fmul_rn(2.0f, cross));
                    mn[p] = fminf(mn[p], d2);        // clamp once at end
                    bool hit = d2 < R2C;
                    unsigned long long mask = __ballot(hit);
                    if (hit) {
                        int pos = cnt[p] + __builtin_amdgcn_mbcnt_hi(
                                     (unsigned)(mask >> 32),
                                     __builtin_amdgcn_mbcnt_lo((unsigned)mask, 0));
                        if (pos < KK) sidx[8 * w + p][pos] = m;
                    }
                    cnt[p] += __popcll(mask);
                }
            }
            __syncthreads();
        }

        float lsum = 0.0f;
#pragma unroll
        for (int p = 0; p < 8; ++p) {
            int row = 8 * w + p;
            if (lane < KK) {
                int fillv = (cnt[p] > 0) ? sidx[row][0] : 0;
                int v = (lane < cnt[p]) ? sidx[row][lane] : fillv;
                idx_ws[((size_t)(pt0 + row)) * KK + lane] = v;
            }
            float mv = mn[p];
            for (int off = 32; off > 0; off >>= 1)
                mv = fminf(mv, __shfl_xor(mv, off));
            lsum += sqrtf(1e-6f + fmaxf(mv, 0.0f));
        }
        if (lane == 0)
            lossbuf[blk * 4 + w] = lsum * (1.0f / (BB * NN));
    } else if (blk < 512) {
        // ---------------- colmin: 32 m, 8 per wave ----------------
        int blk2 = blk - 256;
        int m0 = blk2 * 32;                  // global knn id (b*MM+m)
        int b = blk2 >> 7;
        const float* pp = points + (size_t)b * 3 * NN;
        const float* kp = knn + (size_t)b * 3 * MM;
        float4 Kp[8];
#pragma unroll
        for (int p = 0; p < 8; ++p) {
            int ml = (m0 & (MM - 1)) + 8 * w + p;
            float x = kp[ml], y = kp[MM + ml], z = kp[2 * MM + ml];
            float e = __fadd_rn(__fadd_rn(__fmul_rn(x, x), __fmul_rn(y, y)),
                                __fmul_rn(z, z));
            Kp[p] = make_float4(x, y, z, e);
        }
        float mn[8];
#pragma unroll
        for (int p = 0; p < 8; ++p) mn[p] = 1e30f;

        for (int ch = 0; ch < 4; ++ch) {
            const float* px = pp + ch * 1024;
#pragma unroll
            for (int j = 0; j < 4; ++j) {
                int i = t + 256 * j;
                float x = px[i], y = px[NN + i], z = px[2 * NN + i];
                float e = __fadd_rn(__fadd_rn(__fmul_rn(x, x), __fmul_rn(y, y)),
                                    __fmul_rn(z, z));
                tile[i] = make_float4(x, y, z, e);
            }
            __syncthreads();
#pragma unroll 1
            for (int i = 0; i < 16; ++i) {
                float4 p4 = tile[i * 64 + lane];
#pragma unroll
                for (int p = 0; p < 8; ++p) {
                    float cross = __builtin_fmaf(p4.z, Kp[p].z,
                                  __builtin_fmaf(p4.y, Kp[p].y,
                                                 __fmul_rn(p4.x, Kp[p].x)));
                    float d2 = __fsub_rn(__fadd_rn(p4.w, Kp[p].w),
                                         __fmul_rn(2.0f, cross));
                    mn[p] = fminf(mn[p], d2);
                }
            }
            __syncthreads();
        }

        float lsum = 0.0f;
#pragma unroll
        for (int p = 0; p < 8; ++p) {
            float mv = mn[p];
            for (int off = 32; off > 0; off >>= 1)
                mv = fminf(mv, __shfl_xor(mv, off));
            lsum += sqrtf(1e-6f + fmaxf(mv, 0.0f));
        }
        if (lane == 0)
            lossbuf[1024 + blk2 * 4 + w] = lsum * (1.0f / (BB * MM));
    } else if (blk < 640) {
        // ---------------- feat transpose ----------------
        float (*tl)[65] = (float (*)[65])SM;
        int tb = blk - 512;                     // 128 tiles
        int b = tb / (MM / 64);
        int m0 = (tb % (MM / 64)) * 64;
        int mi = t & 63, cq = t >> 6;
        const float* src = feat + (size_t)b * CC * MM;
#pragma unroll
        for (int r = 0; r < 16; ++r) {
            int c = cq * 16 + r;
            tl[mi][c] = src[(size_t)c * MM + m0 + mi];
        }
        __syncthreads();
        int ci = t & 63, mq = t >> 6;
        _Float16* dst = featH + ((size_t)b * MM + m0) * CC;
#pragma unroll
        for (int r = 0; r < 16; ++r) {
            int mm = mq * 16 + r;
            dst[(size_t)mm * CC + ci] = (_Float16)tl[mm][ci];
        }
    } else {
        // ---------------- weight pack ----------------
        int tt = (blk - 640) * 256 + t;         // < 12288
        if (tt < 128 * 96) {
            int r = tt / 96, k = tt - r * 96;
            w1h[tt] = (_Float16)((k < 68) ? w1[r * 68 + k] : 0.0f);
        }
        if (tt < 64 * 128) w2h[tt] = (_Float16)w2[tt];
        if (tt < 64 * 64)  w3h[tt] = (_Float16)w3[tt];
    }
}

// ---------------------------------------------------------------------------
// Dispatch 2: MFMA MLP. 2048 blocks x 4 points; 2 passes of 64 columns per
// block sharing one weight-fragment preload (halves the 200 MB aggregate
// weight reload of the 4096-block version). LDS 30720 B -> 4 blocks/CU.
// Block 0 additionally sums the 2048 loss partial slots (stream-ordered).
// A-frag: A[m=lane&15][k=quad*8+j]; C-frag: col=lane&15, row=quad*4+reg.
// ---------------------------------------------------------------------------
__launch_bounds__(256, 4)
__global__ void mlp_kernel(const float* __restrict__ points,
                           const float* __restrict__ knn,
                           const _Float16* __restrict__ featH,
                           const int* __restrict__ idx_ws,
                           const _Float16* __restrict__ w1h, const float* __restrict__ b1,
                           const _Float16* __restrict__ w2h, const float* __restrict__ b2,
                           const _Float16* __restrict__ w3h, const float* __restrict__ b3,
                           const float* __restrict__ lossbuf,
                           float* __restrict__ out) {
    __shared__ __align__(16) _Float16 SM[TC * XS + TC * H1S];  // 30720 B
    _Float16* X  = SM;
    _Float16* H2 = SM;             // aliases X (dead after layer-1 barrier)
    _Float16* H1 = SM + TC * XS;
    __shared__ float ws4[4];

    int t = threadIdx.x;

    // ---- fused loss reduction (block 0 only) ----
    if (blockIdx.x == 0) {
        float s = 0.0f;
#pragma unroll
        for (int q = 0; q < 8; ++q) s += lossbuf[t + 256 * q];
        for (int off = 32; off > 0; off >>= 1) s += __shfl_xor(s, off);
        if ((t & 63) == 0) ws4[t >> 6] = s;
        __syncthreads();
        if (t == 0)
            out[(size_t)BB * 64 * NN] = ws4[0] + ws4[1] + ws4[2] + ws4[3];
        __syncthreads();
    }

    int point0 = blockIdx.x * 4;
    int b = point0 >> 12;
    int n0 = point0 & (NN - 1);
    const float* pp = points + (size_t)b * 3 * NN;
    const float* kp = knn + (size_t)b * 3 * MM;

    int w = t >> 6, l = t & 63;
    int quad = l >> 4, lc = l & 15;

    // ---- preload A-fragments (weights) once for both passes ----
    v8h a1[2][3], a2[4], a3[2];
#pragma unroll
    for (int rt = 0; rt < 2; ++rt)
#pragma unroll
        for (int ks = 0; ks < 3; ++ks)
            a1[rt][ks] = *(const v8h*)(w1h + (32 * w + 16 * rt + lc) * 96 + 32 * ks + 8 * quad);
#pragma unroll
    for (int ks = 0; ks < 4; ++ks)
        a2[ks] = *(const v8h*)(w2h + (16 * w + lc) * 128 + 32 * ks + 8 * quad);
#pragma unroll
    for (int ks = 0; ks < 2; ++ks)
        a3[ks] = *(const v8h*)(w3h + (16 * w + lc) * 64 + 32 * ks + 8 * quad);

    v4f bias1a = *(const v4f*)(b1 + 32 * w + 4 * quad);
    v4f bias1b = *(const v4f*)(b1 + 32 * w + 16 + 4 * quad);
    v4f bias2  = *(const v4f*)(b2 + 16 * w + 4 * quad);
    v4f bias3  = *(const v4f*)(b3 + 16 * w + 4 * quad);

#pragma unroll 1
    for (int ps = 0; ps < 2; ++ps) {
        // ---- stage X tile: 4 threads per column (2 points x 32 k) ----
        {
            int col = t >> 2, h = t & 3;
            int pl = col >> 5, kk = col & 31;
            int n = n0 + 2 * ps + pl;
            int id = idx_ws[(((size_t)b * NN + n) << 5) + kk];
            const v8h* src = (const v8h*)(featH + ((size_t)(b * MM + id)) * CC) + h * 2;
            v8h f0 = src[0], f1 = src[1];
            v8h* dst = (v8h*)(X + col * XS) + h * 2;
            dst[0] = f0; dst[1] = f1;
            v8h mv = {(_Float16)0.f, (_Float16)0.f, (_Float16)0.f, (_Float16)0.f,
                      (_Float16)0.f, (_Float16)0.f, (_Float16)0.f, (_Float16)0.f};
            if (h == 0) {
                float px = pp[n], py = pp[NN + n], pz = pp[2 * NN + n];
                float kx = kp[id], ky = kp[MM + id], kz = kp[2 * MM + id];
                float dx = kx - px, dy = ky - py, dz = kz - pz;
                float dd = __fadd_rn(__fadd_rn(__fmul_rn(dx, dx), __fmul_rn(dy, dy)),
                                     __fmul_rn(dz, dz));
                mv[0] = (_Float16)dx; mv[1] = (_Float16)dy;
                mv[2] = (_Float16)dz; mv[3] = (_Float16)dd;
            }
            *((v8h*)(X + col * XS + 64) + h) = mv;   // meta + zero-pad [64,96)
        }
        __syncthreads();

        // ---- layer 1: H1(128 x 64cols) = W1 x X ----
#pragma unroll 1
        for (int ct = 0; ct < 4; ++ct) {
            int colb = 16 * ct + lc;
            v4f acc0 = bias1a, acc1 = bias1b;
#pragma unroll
            for (int ks = 0; ks < 3; ++ks) {
                v8h bx = *(const v8h*)(X + colb * XS + 32 * ks + 8 * quad);
                acc0 = __builtin_amdgcn_mfma_f32_16x16x32_f16(a1[0][ks], bx, acc0, 0, 0, 0);
                acc1 = __builtin_amdgcn_mfma_f32_16x16x32_f16(a1[1][ks], bx, acc1, 0, 0, 0);
            }
            v4h h0, h1v;
#pragma unroll
            for (int r = 0; r < 4; ++r) {
                h0[r]  = (_Float16)fmaxf(acc0[r], 0.0f);
                h1v[r] = (_Float16)fmaxf(acc1[r], 0.0f);
            }
            *(v4h*)(H1 + colb * H1S + 32 * w + 4 * quad)      = h0;
            *(v4h*)(H1 + colb * H1S + 32 * w + 16 + 4 * quad) = h1v;
        }
        __syncthreads();   // X fully consumed; H2 may now overwrite it

        // ---- layer 2: H2(64 x 64cols) = W2 x H1 ----
#pragma unroll 1
        for (int ct = 0; ct < 4; ++ct) {
            int colb = 16 * ct + lc;
            v4f acc = bias2;
#pragma unroll
            for (int ks = 0; ks < 4; ++ks) {
                v8h bx = *(const v8h*)(H1 + colb * H1S + 32 * ks + 8 * quad);
                acc = __builtin_amdgcn_mfma_f32_16x16x32_f16(a2[ks], bx, acc, 0, 0, 0);
            }
            v4h h;
#pragma unroll
            for (int r = 0; r < 4; ++r) h[r] = (_Float16)fmaxf(acc[r], 0.0f);
            *(v4h*)(H2 + colb * H2S + 16 * w + 4 * quad) = h;
        }
        __syncthreads();

        // ---- layer 3 + ReLU + sum over k + store agg ----
#pragma unroll 1
        for (int p = 0; p < 2; ++p) {
            int cA = (2 * p) * 16 + lc, cB = (2 * p + 1) * 16 + lc;
            v4f accA = bias3, accB = bias3;
#pragma unroll
            for (int ks = 0; ks < 2; ++ks) {
                v8h bA = *(const v8h*)(H2 + cA * H2S + 32 * ks + 8 * quad);
                v8h bB = *(const v8h*)(H2 + cB * H2S + 32 * ks + 8 * quad);
                accA = __builtin_amdgcn_mfma_f32_16x16x32_f16(a3[ks], bA, accA, 0, 0, 0);
                accB = __builtin_amdgcn_mfma_f32_16x16x32_f16(a3[ks], bB, accB, 0, 0, 0);
            }
            v4f s;
#pragma unroll
            for (int r = 0; r < 4; ++r)
                s[r] = fmaxf(accA[r], 0.0f) + fmaxf(accB[r], 0.0f);
#pragma unroll
            for (int off = 1; off < 16; off <<= 1) {
#pragma unroll
                for (int r = 0; r < 4; ++r) s[r] += __shfl_xor(s[r], off);
            }
            if (lc == 0) {
                int n = n0 + 2 * ps + p;
                int rowb = 16 * w + 4 * quad;
#pragma unroll
                for (int r = 0; r < 4; ++r)
                    out[((size_t)(b * 64 + rowb + r)) * NN + n] = s[r];
            }
        }
        __syncthreads();   // protect X/H1 before next pass staging
    }
}

// ---------------------------------------------------------------------------
extern "C" void kernel_launch(void* const* d_in, const int* in_sizes, int n_in,
                              void* d_out, int out_size, void* d_ws, size_t ws_size,
                              hipStream_t stream) {
    const float* points = (const float*)d_in[0];
    const float* knn    = (const float*)d_in[1];
    const float* feat   = (const float*)d_in[2];
    const float* w1 = (const float*)d_in[3];
    const float* b1 = (const float*)d_in[4];
    const float* w2 = (const float*)d_in[5];
    const float* b2 = (const float*)d_in[6];
    const float* w3 = (const float*)d_in[7];
    const float* b3 = (const float*)d_in[8];
    float* out = (float*)d_out;

    char* ws = (char*)d_ws;
    _Float16*  featH   = (_Float16*)ws;                  // 1048576 B
    int*       idx_ws  = (int*)(ws + 1048576);           // 1048576 B
    _Float16*  w1h     = (_Float16*)(ws + 2097152);      // 24576 B
    _Float16*  w2h     = (_Float16*)(ws + 2121728);      // 16384 B
    _Float16*  w3h     = (_Float16*)(ws + 2138112);      // 8192 B
    float*     lossbuf = (float*)(ws + 2146304);         // 8192 B (2048 slots)

    scan_setup_kernel<<<688, 256, 0, stream>>>(points, knn, feat, w1, w2, w3,
                                               featH, w1h, w2h, w3h,
                                               idx_ws, lossbuf);
    mlp_kernel<<<(BB * NN) / 4, 256, 0, stream>>>(points, knn, featH, idx_ws,
                                                  w1h, b1, w2h, b2, w3h, b3,
                                                  lossbuf, out);
}

// Round 10
// 120.402 us; speedup vs baseline: 1.0950x; 1.0950x over previous
//
#include <hip/hip_runtime.h>
#include <cstdint>

#define BB 2
#define NN 4096
#define MM 4096
#define KK 32
#define CC 64
#define R2C 0.0064f   // RADIUS^2

typedef _Float16 v8h __attribute__((ext_vector_type(8)));
typedef _Float16 v4h __attribute__((ext_vector_type(4)));
typedef float    v4f __attribute__((ext_vector_type(4)));

#define TC  64     // MLP columns per block
#define XS  104    // X  stride (f16): 96 + 8 pad
#define H1S 136    // H1 stride: 128 + 8
#define H2S 72     // H2 stride: 64 + 8

// ---------------------------------------------------------------------------
// Dispatch 1: scan + setup in one kernel (no inter-block dependencies).
//   blocks [   0,  512): SELECT 16 points (4/wave). knn chunks staged to LDS
//                        from the RAW (B,3,M) layout with |k|^2 computed in
//                        the staging pass (identical fp32 op order ->
//                        identical d2 bits -> identical selection). Ballot-
//                        compaction of the first KK ascending in-radius m ==
//                        reference top_k-of-masked-index. Row-min -> unique
//                        loss slot.
//   blocks [ 512, 1024): COLMIN 16 m (4/wave), points staged likewise.
//   blocks [1024, 1152): transpose feat (B,C,M) -> featH (B,M,C) f16.
//   blocks [1152, 1200): pack weights to f16 A-operand layouts.
// Loss: per-wave plain store to a unique slot (no atomics, no zeroing).
// NOTE (R9 lesson): 16 pts/block @ 4/wave is the TLP sweet spot — 32/block
// halves block count and doubles the serialized ballot chain per wave.
// ---------------------------------------------------------------------------
__launch_bounds__(256)
__global__ void scan_setup_kernel(const float* __restrict__ points,
                                  const float* __restrict__ knn,
                                  const float* __restrict__ feat,
                                  const float* __restrict__ w1,
                                  const float* __restrict__ w2,
                                  const float* __restrict__ w3,
                                  _Float16* __restrict__ featH,
                                  _Float16* __restrict__ w1h,
                                  _Float16* __restrict__ w2h,
                                  _Float16* __restrict__ w3h,
                                  int* __restrict__ idx_ws,
                                  float* __restrict__ lossbuf) {
    __shared__ __align__(16) char SM[16640];   // union: float4[1024] | float[64][65]
    __shared__ int sidx[16][KK];
    float4* tile = (float4*)SM;
    int t = threadIdx.x;
    int w = t >> 6, lane = t & 63;
    int blk = blockIdx.x;

    if (blk < 512) {
        // ---------------- select ----------------
        int pt0 = blk * 16;                  // global point id (b*NN+n)
        int b = blk >> 8;
        const float* pp = points + (size_t)b * 3 * NN;
        const float* kp = knn + (size_t)b * 3 * MM;
        float4 P[4];
#pragma unroll
        for (int p = 0; p < 4; ++p) {
            int nl = (pt0 & (NN - 1)) + 4 * w + p;
            float x = pp[nl], y = pp[NN + nl], z = pp[2 * NN + nl];
            float e = __fadd_rn(__fadd_rn(__fmul_rn(x, x), __fmul_rn(y, y)),
                                __fmul_rn(z, z));
            P[p] = make_float4(x, y, z, e);
        }
        int cnt[4] = {0, 0, 0, 0};
        float mn[4] = {1e30f, 1e30f, 1e30f, 1e30f};

        for (int ch = 0; ch < 4; ++ch) {
            const float* kx = kp + ch * 1024;
#pragma unroll
            for (int j = 0; j < 4; ++j) {
                int i = t + 256 * j;
                float x = kx[i], y = kx[MM + i], z = kx[2 * MM + i];
                float e = __fadd_rn(__fadd_rn(__fmul_rn(x, x), __fmul_rn(y, y)),
                                    __fmul_rn(z, z));
                tile[i] = make_float4(x, y, z, e);
            }
            __syncthreads();
#pragma unroll 2
            for (int i = 0; i < 16; ++i) {
                float4 k4 = tile[i * 64 + lane];
                int m = ch * 1024 + i * 64 + lane;
#pragma unroll
                for (int p = 0; p < 4; ++p) {
                    float cross = __builtin_fmaf(P[p].z, k4.z,
                                  __builtin_fmaf(P[p].y, k4.y,
                                                 __fmul_rn(P[p].x, k4.x)));
                    float d2 = __fsub_rn(__fadd_rn(P[p].w, k4.w),
                                         __fmul_rn(2.0f, cross));
                    mn[p] = fminf(mn[p], d2);        // clamp once at end
                    bool hit = d2 < R2C;
                    unsigned long long mask = __ballot(hit);
                    if (hit) {
                        int pos = cnt[p] + __builtin_amdgcn_mbcnt_hi(
                                     (unsigned)(mask >> 32),
                                     __builtin_amdgcn_mbcnt_lo((unsigned)mask, 0));
                        if (pos < KK) sidx[4 * w + p][pos] = m;
                    }
                    cnt[p] += __popcll(mask);
                }
            }
            __syncthreads();
        }

        float lsum = 0.0f;
#pragma unroll
        for (int p = 0; p < 4; ++p) {
            int row = 4 * w + p;
            if (lane < KK) {
                int fillv = (cnt[p] > 0) ? sidx[row][0] : 0;
                int v = (lane < cnt[p]) ? sidx[row][lane] : fillv;
                idx_ws[((size_t)(pt0 + row)) * KK + lane] = v;
            }
            float mv = mn[p];
            for (int off = 32; off > 0; off >>= 1)
                mv = fminf(mv, __shfl_xor(mv, off));
            lsum += sqrtf(1e-6f + fmaxf(mv, 0.0f));
        }
        if (lane == 0)
            lossbuf[blk * 4 + w] = lsum * (1.0f / (BB * NN));
    } else if (blk < 1024) {
        // ---------------- colmin ----------------
        int blk2 = blk - 512;
        int m0 = blk2 * 16;                  // global knn id (b*MM+m)
        int b = blk2 >> 8;
        const float* pp = points + (size_t)b * 3 * NN;
        const float* kp = knn + (size_t)b * 3 * MM;
        float4 Kp[4];
#pragma unroll
        for (int p = 0; p < 4; ++p) {
            int ml = (m0 & (MM - 1)) + 4 * w + p;
            float x = kp[ml], y = kp[MM + ml], z = kp[2 * MM + ml];
            float e = __fadd_rn(__fadd_rn(__fmul_rn(x, x), __fmul_rn(y, y)),
                                __fmul_rn(z, z));
            Kp[p] = make_float4(x, y, z, e);
        }
        float mn[4] = {1e30f, 1e30f, 1e30f, 1e30f};

        for (int ch = 0; ch < 4; ++ch) {
            const float* px = pp + ch * 1024;
#pragma unroll
            for (int j = 0; j < 4; ++j) {
                int i = t + 256 * j;
                float x = px[i], y = px[NN + i], z = px[2 * NN + i];
                float e = __fadd_rn(__fadd_rn(__fmul_rn(x, x), __fmul_rn(y, y)),
                                    __fmul_rn(z, z));
                tile[i] = make_float4(x, y, z, e);
            }
            __syncthreads();
#pragma unroll 2
            for (int i = 0; i < 16; ++i) {
                float4 p4 = tile[i * 64 + lane];
#pragma unroll
                for (int p = 0; p < 4; ++p) {
                    float cross = __builtin_fmaf(p4.z, Kp[p].z,
                                  __builtin_fmaf(p4.y, Kp[p].y,
                                                 __fmul_rn(p4.x, Kp[p].x)));
                    float d2 = __fsub_rn(__fadd_rn(p4.w, Kp[p].w),
                                         __fmul_rn(2.0f, cross));
                    mn[p] = fminf(mn[p], d2);
                }
            }
            __syncthreads();
        }

        float lsum = 0.0f;
#pragma unroll
        for (int p = 0; p < 4; ++p) {
            float mv = mn[p];
            for (int off = 32; off > 0; off >>= 1)
                mv = fminf(mv, __shfl_xor(mv, off));
            lsum += sqrtf(1e-6f + fmaxf(mv, 0.0f));
        }
        if (lane == 0)
            lossbuf[2048 + blk2 * 4 + w] = lsum * (1.0f / (BB * MM));
    } else if (blk < 1152) {
        // ---------------- feat transpose ----------------
        float (*tl)[65] = (float (*)[65])SM;
        int tb = blk - 1024;                    // 128 tiles
        int b = tb / (MM / 64);
        int m0 = (tb % (MM / 64)) * 64;
        int mi = t & 63, cq = t >> 6;
        const float* src = feat + (size_t)b * CC * MM;
#pragma unroll
        for (int r = 0; r < 16; ++r) {
            int c = cq * 16 + r;
            tl[mi][c] = src[(size_t)c * MM + m0 + mi];
        }
        __syncthreads();
        int ci = t & 63, mq = t >> 6;
        _Float16* dst = featH + ((size_t)b * MM + m0) * CC;
#pragma unroll
        for (int r = 0; r < 16; ++r) {
            int mm = mq * 16 + r;
            dst[(size_t)mm * CC + ci] = (_Float16)tl[mm][ci];
        }
    } else {
        // ---------------- weight pack ----------------
        int tt = (blk - 1152) * 256 + t;        // < 12288
        if (tt < 128 * 96) {
            int r = tt / 96, k = tt - r * 96;
            w1h[tt] = (_Float16)((k < 68) ? w1[r * 68 + k] : 0.0f);
        }
        if (tt < 64 * 128) w2h[tt] = (_Float16)w2[tt];
        if (tt < 64 * 64)  w3h[tt] = (_Float16)w3[tt];
    }
}

// ---------------------------------------------------------------------------
// Dispatch 2: MFMA MLP. WG = 256 thr = 4 waves, 64 columns (2 points x 32 k).
// LDS: H2 aliases X (X dead after layer-1 barrier) -> 30720 B, 4 blocks/CU.
// 4096 independent single-pass blocks (R9 lesson: do NOT serialize passes
// inside a block to save weight reloads — TLP beats L2 locality here).
// Block 0 additionally sums the 4096 loss partial slots (stream-ordered).
// A-frag: A[m=lane&15][k=quad*8+j]; C-frag: col=lane&15, row=quad*4+reg.
// ---------------------------------------------------------------------------
__launch_bounds__(256, 4)
__global__ void mlp_kernel(const float* __restrict__ points,
                           const float* __restrict__ knn,
                           const _Float16* __restrict__ featH,
                           const int* __restrict__ idx_ws,
                           const _Float16* __restrict__ w1h, const float* __restrict__ b1,
                           const _Float16* __restrict__ w2h, const float* __restrict__ b2,
                           const _Float16* __restrict__ w3h, const float* __restrict__ b3,
                           const float* __restrict__ lossbuf,
                           float* __restrict__ out) {
    __shared__ __align__(16) _Float16 SM[TC * XS + TC * H1S];  // 30720 B
    _Float16* X  = SM;
    _Float16* H2 = SM;             // aliases X (dead after layer-1 barrier)
    _Float16* H1 = SM + TC * XS;
    __shared__ float ws4[4];

    int t = threadIdx.x;

    // ---- fused loss reduction (block 0 only) ----
    if (blockIdx.x == 0) {
        float s = 0.0f;
#pragma unroll
        for (int q = 0; q < 16; ++q) s += lossbuf[t + 256 * q];
        for (int off = 32; off > 0; off >>= 1) s += __shfl_xor(s, off);
        if ((t & 63) == 0) ws4[t >> 6] = s;
        __syncthreads();
        if (t == 0)
            out[(size_t)BB * 64 * NN] = ws4[0] + ws4[1] + ws4[2] + ws4[3];
    }

    int point0 = blockIdx.x * 2;
    int b = point0 >> 12;
    int n0 = point0 & (NN - 1);
    const float* pp = points + (size_t)b * 3 * NN;
    const float* kp = knn + (size_t)b * 3 * MM;

    // ---- stage X tile: 4 threads per column ----
    {
        int col = t >> 2, h = t & 3;
        int pl = col >> 5, kk = col & 31;
        int n = n0 + pl;
        int id = idx_ws[(((size_t)b * NN + n) << 5) + kk];
        const v8h* src = (const v8h*)(featH + ((size_t)(b * MM + id)) * CC) + h * 2;
        v8h f0 = src[0], f1 = src[1];
        v8h* dst = (v8h*)(X + col * XS) + h * 2;
        dst[0] = f0; dst[1] = f1;
        v8h mv = {(_Float16)0.f, (_Float16)0.f, (_Float16)0.f, (_Float16)0.f,
                  (_Float16)0.f, (_Float16)0.f, (_Float16)0.f, (_Float16)0.f};
        if (h == 0) {
            float px = pp[n], py = pp[NN + n], pz = pp[2 * NN + n];
            float kx = kp[id], ky = kp[MM + id], kz = kp[2 * MM + id];
            float dx = kx - px, dy = ky - py, dz = kz - pz;
            float dd = __fadd_rn(__fadd_rn(__fmul_rn(dx, dx), __fmul_rn(dy, dy)),
                                 __fmul_rn(dz, dz));
            mv[0] = (_Float16)dx; mv[1] = (_Float16)dy;
            mv[2] = (_Float16)dz; mv[3] = (_Float16)dd;
        }
        *((v8h*)(X + col * XS + 64) + h) = mv;   // meta + zero-pad [64,96)
    }

    int w = t >> 6, l = t & 63;
    int quad = l >> 4, lc = l & 15;

    // ---- preload A-fragments (weights) ----
    v8h a1[2][3], a2[4], a3[2];
#pragma unroll
    for (int rt = 0; rt < 2; ++rt)
#pragma unroll
        for (int ks = 0; ks < 3; ++ks)
            a1[rt][ks] = *(const v8h*)(w1h + (32 * w + 16 * rt + lc) * 96 + 32 * ks + 8 * quad);
#pragma unroll
    for (int ks = 0; ks < 4; ++ks)
        a2[ks] = *(const v8h*)(w2h + (16 * w + lc) * 128 + 32 * ks + 8 * quad);
#pragma unroll
    for (int ks = 0; ks < 2; ++ks)
        a3[ks] = *(const v8h*)(w3h + (16 * w + lc) * 64 + 32 * ks + 8 * quad);

    v4f bias1a = *(const v4f*)(b1 + 32 * w + 4 * quad);
    v4f bias1b = *(const v4f*)(b1 + 32 * w + 16 + 4 * quad);
    v4f bias2  = *(const v4f*)(b2 + 16 * w + 4 * quad);
    v4f bias3  = *(const v4f*)(b3 + 16 * w + 4 * quad);

    __syncthreads();

    // ---- layer 1: H1(128 x 64cols) = W1 x X ----
#pragma unroll 1
    for (int ct = 0; ct < 4; ++ct) {
        int colb = 16 * ct + lc;
        v4f acc0 = bias1a, acc1 = bias1b;
#pragma unroll
        for (int ks = 0; ks < 3; ++ks) {
            v8h bx = *(const v8h*)(X + colb * XS + 32 * ks + 8 * quad);
            acc0 = __builtin_amdgcn_mfma_f32_16x16x32_f16(a1[0][ks], bx, acc0, 0, 0, 0);
            acc1 = __builtin_amdgcn_mfma_f32_16x16x32_f16(a1[1][ks], bx, acc1, 0, 0, 0);
        }
        v4h h0, h1v;
#pragma unroll
        for (int r = 0; r < 4; ++r) {
            h0[r]  = (_Float16)fmaxf(acc0[r], 0.0f);
            h1v[r] = (_Float16)fmaxf(acc1[r], 0.0f);
        }
        *(v4h*)(H1 + colb * H1S + 32 * w + 4 * quad)      = h0;
        *(v4h*)(H1 + colb * H1S + 32 * w + 16 + 4 * quad) = h1v;
    }
    __syncthreads();   // X fully consumed; H2 may now overwrite it

    // ---- layer 2: H2(64 x 64cols) = W2 x H1 ----
#pragma unroll 1
    for (int ct = 0; ct < 4; ++ct) {
        int colb = 16 * ct + lc;
        v4f acc = bias2;
#pragma unroll
        for (int ks = 0; ks < 4; ++ks) {
            v8h bx = *(const v8h*)(H1 + colb * H1S + 32 * ks + 8 * quad);
            acc = __builtin_amdgcn_mfma_f32_16x16x32_f16(a2[ks], bx, acc, 0, 0, 0);
        }
        v4h h;
#pragma unroll
        for (int r = 0; r < 4; ++r) h[r] = (_Float16)fmaxf(acc[r], 0.0f);
        *(v4h*)(H2 + colb * H2S + 16 * w + 4 * quad) = h;
    }
    __syncthreads();

    // ---- layer 3 + ReLU + sum over k + store agg ----
#pragma unroll 1
    for (int p = 0; p < 2; ++p) {
        int cA = (2 * p) * 16 + lc, cB = (2 * p + 1) * 16 + lc;
        v4f accA = bias3, accB = bias3;
#pragma unroll
        for (int ks = 0; ks < 2; ++ks) {
            v8h bA = *(const v8h*)(H2 + cA * H2S + 32 * ks + 8 * quad);
            v8h bB = *(const v8h*)(H2 + cB * H2S + 32 * ks + 8 * quad);
            accA = __builtin_amdgcn_mfma_f32_16x16x32_f16(a3[ks], bA, accA, 0, 0, 0);
            accB = __builtin_amdgcn_mfma_f32_16x16x32_f16(a3[ks], bB, accB, 0, 0, 0);
        }
        v4f s;
#pragma unroll
        for (int r = 0; r < 4; ++r)
            s[r] = fmaxf(accA[r], 0.0f) + fmaxf(accB[r], 0.0f);
#pragma unroll
        for (int off = 1; off < 16; off <<= 1) {
#pragma unroll
            for (int r = 0; r < 4; ++r) s[r] += __shfl_xor(s[r], off);
        }
        if (lc == 0) {
            int n = n0 + p;
            int rowb = 16 * w + 4 * quad;
#pragma unroll
            for (int r = 0; r < 4; ++r)
                out[((size_t)(b * 64 + rowb + r)) * NN + n] = s[r];
        }
    }
}

// ---------------------------------------------------------------------------
extern "C" void kernel_launch(void* const* d_in, const int* in_sizes, int n_in,
                              void* d_out, int out_size, void* d_ws, size_t ws_size,
                              hipStream_t stream) {
    const float* points = (const float*)d_in[0];
    const float* knn    = (const float*)d_in[1];
    const float* feat   = (const float*)d_in[2];
    const float* w1 = (const float*)d_in[3];
    const float* b1 = (const float*)d_in[4];
    const float* w2 = (const float*)d_in[5];
    const float* b2 = (const float*)d_in[6];
    const float* w3 = (const float*)d_in[7];
    const float* b3 = (const float*)d_in[8];
    float* out = (float*)d_out;

    char* ws = (char*)d_ws;
    _Float16*  featH   = (_Float16*)ws;                  // 1048576 B
    int*       idx_ws  = (int*)(ws + 1048576);           // 1048576 B
    _Float16*  w1h     = (_Float16*)(ws + 2097152);      // 24576 B
    _Float16*  w2h     = (_Float16*)(ws + 2121728);      // 16384 B
    _Float16*  w3h     = (_Float16*)(ws + 2138112);      // 8192 B
    float*     lossbuf = (float*)(ws + 2146304);         // 16384 B (4096 slots)

    scan_setup_kernel<<<1200, 256, 0, stream>>>(points, knn, feat, w1, w2, w3,
                                                featH, w1h, w2h, w3h,
                                                idx_ws, lossbuf);
    mlp_kernel<<<(BB * NN) / 2, 256, 0, stream>>>(points, knn, featH, idx_ws,
                                                  w1h, b1, w2h, b2, w3h, b3,
                                                  lossbuf, out);
}